// Round 8
// baseline (150.167 us; speedup 1.0000x reference)
//
#include <hip/hip_runtime.h>
#include <hip/hip_bf16.h>

#define DI __device__ __forceinline__

typedef __attribute__((ext_vector_type(8))) short bf16x8;   // 8 bf16 = 4 VGPRs (MFMA A/B frag)
typedef __attribute__((ext_vector_type(4))) float f32x4;    // MFMA C/D frag

constexpr int HW = 4096, CHW = 262144;
constexpr int NC = 34;             // sA cols: 32 px + 2 halo

// ---- workspace layout (bytes), all 16B aligned ----
constexpr size_t OFF_XT   = 0;                       // bf16 NHWC relu(x)      16 MB
constexpr size_t OFF_N1   = 16777216;                // bf16 NHWC relu(n1)     16 MB
constexpr size_t OFF_P3   = 33554432;                // bf16 NHWC p3 = conv1_e1(n2)+b4
constexpr size_t OFF_WB3  = 50331648;                // bf16 [3][9][64oc][64ic]  (frag order)
constexpr size_t OFF_WB1  = OFF_WB3 + 221184;        // bf16 [2][64oc][64ic]
constexpr size_t OFF_BIAS = OFF_WB1 + 16384;         // f32 [5][64]
constexpr size_t OFF_CC   = OFF_BIAS + 1280;         // int[2]

DI int argmax8(const float* __restrict__ a) {
    int best = 0; float bv = a[0];
#pragma unroll
    for (int i = 1; i < 8; ++i) { float v = a[i]; if (v > bv) { bv = v; best = i; } }
    return best;
}

DI short f2bf(float v) {   // fp32 -> bf16 bits (RNE)
    __hip_bfloat16 h = __float2bfloat16(v);
    return __builtin_bit_cast(short, h);
}

// ---- XOR-swizzled sA addressing: logical ic-segment s of column c lives at
// slot (s^c)&7. Keeps 16B frag contiguity; uniform bank spread for b128 ops
// (column stride 64 shorts = 128 B would otherwise alias all banks). ----
DI int saF(int r, int c, int seg) {            // frag base, seg = logical ic>>3
    return (r * NC + c) * 64 + ((seg ^ c) & 7) * 8;
}
DI int saE(int r, int c, int oc) {             // scalar element
    return (r * NC + c) * 64 + (((oc >> 3) ^ c) & 7) * 8 + (oc & 7);
}

// ---------------------------------------------------------------------------
// shared device bodies
// ---------------------------------------------------------------------------
DI void transform_unit(const float* __restrict__ x, short* __restrict__ xT,
                       short* __restrict__ sT, int unit, int t) {
    const int y = unit & 63, n = unit >> 6;
    const int xc = t & 63, c0 = t >> 6;
    const float* __restrict__ src = x + (size_t)(n * 64) * HW + y * 64;
#pragma unroll
    for (int p = 0; p < 16; ++p) {
        const int c = p * 4 + c0;
        sT[xc * 72 + c] = f2bf(fmaxf(src[c * HW + xc], 0.f));
    }
    __syncthreads();
    short* __restrict__ dst = xT + (size_t)((n * 64 + y) * 64) * 64;
    const int cs = t & 7, xr = t >> 3;
#pragma unroll
    for (int p = 0; p < 2; ++p) {
        const int xx = p * 32 + xr;
        *(bf16x8*)(dst + xx * 64 + cs * 8) = *(const bf16x8*)(&sT[xx * 72 + cs * 8]);
    }
}

DI void prep_item(const float* __restrict__ w3, const float* __restrict__ w1,
                  const float* __restrict__ bn, const float* __restrict__ a1,
                  const float* __restrict__ a2, char* __restrict__ ws, int idx) {
    short* __restrict__ wb3  = (short*)(ws + OFF_WB3);
    short* __restrict__ wb1  = (short*)(ws + OFF_WB1);
    float* __restrict__ bias = (float*)(ws + OFF_BIAS);
    int*   __restrict__ cc   = (int*)(ws + OFF_CC);
    const int c1 = 8 * (argmax8(a1) + 1);
    const int c2 = 8 * (argmax8(a2) + 1);

    if (idx < 110592) {                       // wb3 flat = ((e*9+kp)*64+oc)*64+ic
        const int e = idx / 36864, rem = idx % 36864;
        const int kp = rem >> 12, oc = (rem >> 6) & 63, ic = rem & 63;
        const int bnrow = (e == 0) ? 0 : (e == 1) ? 1 : 3;
        const float g = bn[(bnrow * 4 + 0) * 64 + oc];
        const float v = bn[(bnrow * 4 + 3) * 64 + oc];
        const float s = g * rsqrtf(v + 1e-5f);
        const float wv = w3[((e * 64 + oc) * 64 + ic) * 9 + kp];
        wb3[idx] = (oc < c2 && ic < c1) ? f2bf(wv * s) : (short)0;
    } else if (idx < 118784) {                // wb1 flat = (e*64+oc)*64+ic
        const int j = idx - 110592;
        const int e = j >> 12, oc = (j >> 6) & 63, ic = j & 63;
        const int bnrow = (e == 0) ? 2 : 4;
        const float g = bn[(bnrow * 4 + 0) * 64 + oc];
        const float v = bn[(bnrow * 4 + 3) * 64 + oc];
        const float s = g * rsqrtf(v + 1e-5f);
        wb1[j] = (oc < c2 && ic < c1) ? f2bf(w1[(e * 64 + oc) * 64 + ic] * s) : (short)0;
    } else if (idx < 119104) {                // bias
        const int j = idx - 118784;
        const int e = j >> 6, oc = j & 63;
        const float g = bn[(e * 4 + 0) * 64 + oc];
        const float b = bn[(e * 4 + 1) * 64 + oc];
        const float m = bn[(e * 4 + 2) * 64 + oc];
        const float v = bn[(e * 4 + 3) * 64 + oc];
        bias[j] = (oc < c2) ? (b - m * g * rsqrtf(v + 1e-5f)) : 0.f;
    } else if (idx == 119104) {
        cc[0] = c1; cc[1] = c2;
    }
}

// stage sA (6 rows x 34 cols halo x live ic) from a bf16 NHWC tensor
DI void stage_sA(const short* __restrict__ src, short* __restrict__ sA,
                 int n, int y0, int x0, int SGm, int t) {
    for (int idx = t; idx < 6 * NC * 8; idx += 256) {
        const int r = idx / (NC * 8), rem = idx - r * (NC * 8), c = rem >> 3, sg = rem & 7;
        if (sg < SGm) {
            const int gy = y0 + r - 1, gx = x0 + c - 1;
            bf16x8 v = 0;
            if ((unsigned)gy < 64u && (unsigned)gx < 64u)
                v = *(const bf16x8*)(src + ((n * 64 + gy) * 64 + gx) * 64 + sg * 8);
            *(bf16x8*)(&sA[saF(r, c, sg)]) = v;
        }
    }
}

// coalesced store of one 32-px row (sA cols 1..32, all 64 ch) to NHWC global.
// dst pre-offset to ((n*64+y)*64 + x0)*64. 4 KB contiguous per wave.
DI void store_row32(const short* __restrict__ sA, int row,
                    short* __restrict__ dst, int l) {
#pragma unroll
    for (int i = 0; i < 4; ++i) {
        const int c = i * 8 + (l >> 3), sg = l & 7;
        *(bf16x8*)(dst + c * 64 + sg * 8) = *(const bf16x8*)(&sA[saF(row, c + 1, sg)]);
    }
}

// ---------------------------------------------------------------------------
// K0: transform (blocks 0..2047) + prep (blocks 2048..2559)
// ---------------------------------------------------------------------------
__global__ __launch_bounds__(256) void prep_transform_kernel(
    const float* __restrict__ x, const float* __restrict__ w3,
    const float* __restrict__ w1, const float* __restrict__ bn,
    const float* __restrict__ a1, const float* __restrict__ a2,
    char* __restrict__ ws) {
    __shared__ short sT[64 * 72];
    const int t = threadIdx.x;
    if (blockIdx.x < 2048) {
        transform_unit(x, (short*)(ws + OFF_XT), sT, blockIdx.x, t);
        return;
    }
    prep_item(w3, w1, bn, a1, a2, ws, (blockIdx.x - 2048) * 256 + t);
}

// ---------------------------------------------------------------------------
// K1: fused mid (4 rows x 32 px tile). Dual conv3 (e0->acc1=n1, e1->acc2) off
// one sA staging of xT; per-wave chain: n1 -> own sA row -> coalesced global
// store -> conv1_e0 into acc2 (=n2) -> conv1_e1 -> p3 -> store. 26.1 KB LDS,
// launch_bounds(256,3) -> 12 waves/CU (occupancy was the R7 bottleneck).
// All register-array indices compile-time (R2 spill lesson).
// ---------------------------------------------------------------------------
__global__ __launch_bounds__(256, 3) void fused_mid_kernel(
    const short* __restrict__ xT, const char* __restrict__ ws,
    short* __restrict__ n1out, short* __restrict__ p3out) {
    __shared__ __align__(16) short sA[6 * NC * 64];   // 26.1 KB
    const int t = threadIdx.x, w = t >> 6, l = t & 63, lm = l & 15, q = l >> 4;
    const int y0 = (blockIdx.x >> 1) * 4, x0 = (blockIdx.x & 1) * 32, n = blockIdx.y;
    const int* cc = (const int*)(ws + OFF_CC);
    const int c1 = __builtin_amdgcn_readfirstlane(cc[0]);
    const int c2 = __builtin_amdgcn_readfirstlane(cc[1]);
    const int SGm = (c1 > 32) ? 8 : 4;
    const float* __restrict__ bias = (const float*)(ws + OFF_BIAS);
    const short* __restrict__ WBe0 = (const short*)(ws + OFF_WB3);
    const short* __restrict__ WBe1 = WBe0 + 36864;
    const short* __restrict__ W1e0 = (const short*)(ws + OFF_WB1);
    const short* __restrict__ W1e1 = W1e0 + 4096;

    f32x4 acc1[2][4], acc2[2][4];
#pragma unroll
    for (int i = 0; i < 2; ++i)
#pragma unroll
        for (int j = 0; j < 4; ++j) { acc1[i][j] = 0.f; acc2[i][j] = 0.f; }

    stage_sA(xT, sA, n, y0, x0, SGm, t);
    __syncthreads();

    // ---- dual conv3 K-loop (barrier-free, sA read-only) ----
    {
        const short* __restrict__ W0 = WBe0;
        const short* __restrict__ W1 = WBe1;
#pragma unroll 1
        for (int ky = 0; ky < 3; ++ky) {
#pragma unroll 1
            for (int kx = 0; kx < 3; ++kx) {
#pragma unroll
                for (int kc = 0; kc < 2; ++kc) {
                    if (kc == 0 || c1 > 32) {
                        bf16x8 af[2], b0[4], b1[4];
#pragma unroll
                        for (int nt = 0; nt < 4; ++nt)
                            if (nt * 16 < c2) {
                                b0[nt] = *(const bf16x8*)(W0 + (nt * 16 + lm) * 64 + kc * 32 + q * 8);
                                b1[nt] = *(const bf16x8*)(W1 + (nt * 16 + lm) * 64 + kc * 32 + q * 8);
                            }
#pragma unroll
                        for (int mt = 0; mt < 2; ++mt)
                            af[mt] = *(const bf16x8*)(&sA[saF(w + ky, mt * 16 + lm + kx, kc * 4 + q)]);
#pragma unroll
                        for (int nt = 0; nt < 4; ++nt)
                            if (nt * 16 < c2) {
#pragma unroll
                                for (int mt = 0; mt < 2; ++mt) {
                                    acc1[mt][nt] = __builtin_amdgcn_mfma_f32_16x16x32_bf16(af[mt], b0[nt], acc1[mt][nt], 0, 0, 0);
                                    acc2[mt][nt] = __builtin_amdgcn_mfma_f32_16x16x32_bf16(af[mt], b1[nt], acc2[mt][nt], 0, 0, 0);
                                }
                            }
                    }
                }
                W0 += 4096; W1 += 4096;
            }
        }
    }

    __syncthreads();   // all waves done reading stage-1 sA; rows become wave-private

    const int y = y0 + w;
    short* __restrict__ n1row = n1out + (size_t)((n * 64 + y) * 64 + x0) * 64;
    short* __restrict__ p3row = p3out + (size_t)((n * 64 + y) * 64 + x0) * 64;

    // epi1: n1 = relu(acc1 + b0) -> own sA row (cols 1..32, all 64 oc)
#pragma unroll
    for (int nt = 0; nt < 4; ++nt) {
        const int oc = nt * 16 + lm;
        const float bv = bias[oc];
#pragma unroll
        for (int mt = 0; mt < 2; ++mt)
#pragma unroll
            for (int r = 0; r < 4; ++r) {
                const int xp = mt * 16 + q * 4 + r;
                sA[saE(w + 1, xp + 1, oc)] = f2bf(fmaxf(acc1[mt][nt][r] + bv, 0.f));
            }
    }
    store_row32(sA, w + 1, n1row, l);

    // conv1_e0(n1) += acc2 (own row)
#pragma unroll
    for (int kc = 0; kc < 2; ++kc) {
        if (kc == 0 || c1 > 32) {
            bf16x8 af[2], bfr[4];
#pragma unroll
            for (int mt = 0; mt < 2; ++mt)
                af[mt] = *(const bf16x8*)(&sA[saF(w + 1, mt * 16 + lm + 1, kc * 4 + q)]);
#pragma unroll
            for (int nt = 0; nt < 4; ++nt)
                if (nt * 16 < c2)
                    bfr[nt] = *(const bf16x8*)(W1e0 + (nt * 16 + lm) * 64 + kc * 32 + q * 8);
#pragma unroll
            for (int nt = 0; nt < 4; ++nt)
                if (nt * 16 < c2) {
#pragma unroll
                    for (int mt = 0; mt < 2; ++mt)
                        acc2[mt][nt] = __builtin_amdgcn_mfma_f32_16x16x32_bf16(af[mt], bfr[nt], acc2[mt][nt], 0, 0, 0);
                }
        }
    }

    // epi2: n2 = relu(acc2 + b1 + b2) -> own sA row
#pragma unroll
    for (int nt = 0; nt < 4; ++nt) {
        const int oc = nt * 16 + lm;
        const float bv = bias[64 + oc] + bias[128 + oc];
#pragma unroll
        for (int mt = 0; mt < 2; ++mt)
#pragma unroll
            for (int r = 0; r < 4; ++r) {
                const int xp = mt * 16 + q * 4 + r;
                sA[saE(w + 1, xp + 1, oc)] = f2bf(fmaxf(acc2[mt][nt][r] + bv, 0.f));
            }
    }

    // conv1_e1(n2) -> acc3 (reuses acc1's registers)
    {
        f32x4 acc3[2][4];
#pragma unroll
        for (int i = 0; i < 2; ++i)
#pragma unroll
            for (int j = 0; j < 4; ++j) acc3[i][j] = 0.f;
#pragma unroll
        for (int kc = 0; kc < 2; ++kc) {
            if (kc == 0 || c1 > 32) {
                bf16x8 af[2], bfr[4];
#pragma unroll
                for (int mt = 0; mt < 2; ++mt)
                    af[mt] = *(const bf16x8*)(&sA[saF(w + 1, mt * 16 + lm + 1, kc * 4 + q)]);
#pragma unroll
                for (int nt = 0; nt < 4; ++nt)
                    if (nt * 16 < c2)
                        bfr[nt] = *(const bf16x8*)(W1e1 + (nt * 16 + lm) * 64 + kc * 32 + q * 8);
#pragma unroll
                for (int nt = 0; nt < 4; ++nt)
                    if (nt * 16 < c2) {
#pragma unroll
                        for (int mt = 0; mt < 2; ++mt)
                            acc3[mt][nt] = __builtin_amdgcn_mfma_f32_16x16x32_bf16(af[mt], bfr[nt], acc3[mt][nt], 0, 0, 0);
                    }
            }
        }
#pragma unroll
        for (int nt = 0; nt < 4; ++nt) {
            const int oc = nt * 16 + lm;
            const float bv = bias[256 + oc];
#pragma unroll
            for (int mt = 0; mt < 2; ++mt)
#pragma unroll
                for (int r = 0; r < 4; ++r) {
                    const int xp = mt * 16 + q * 4 + r;
                    sA[saE(w + 1, xp + 1, oc)] = f2bf(acc3[mt][nt][r] + bv);
                }
        }
        store_row32(sA, w + 1, p3row, l);
    }
}

// ---------------------------------------------------------------------------
// K2: d_out = x + conv3_e2(n1) + p3 (4 rows x 32 px tile), LDS-transposed
// coalesced epilogue. 26.1 KB LDS, launch_bounds(256,4) -> 16 waves/CU.
// ---------------------------------------------------------------------------
__global__ __launch_bounds__(256, 4) void final_conv_kernel(
    const short* __restrict__ n1in, const char* __restrict__ ws,
    const float* __restrict__ skip, float* __restrict__ outp) {
    __shared__ __align__(16) short sA[6 * NC * 64];
    const int t = threadIdx.x, w = t >> 6, l = t & 63, lm = l & 15, q = l >> 4;
    const int y0 = (blockIdx.x >> 1) * 4, x0 = (blockIdx.x & 1) * 32, n = blockIdx.y;
    const int* cc = (const int*)(ws + OFF_CC);
    const int c1 = __builtin_amdgcn_readfirstlane(cc[0]);
    const int c2 = __builtin_amdgcn_readfirstlane(cc[1]);
    const int SGm = (c1 > 32) ? 8 : 4;
    const float* __restrict__ bias3 = (const float*)(ws + OFF_BIAS) + 192;
    const short* __restrict__ WBe2 = (const short*)(ws + OFF_WB3) + 2 * 36864;
    const short* __restrict__ p3in = (const short*)(ws + OFF_P3);

    f32x4 acc[2][4];
#pragma unroll
    for (int i = 0; i < 2; ++i)
#pragma unroll
        for (int j = 0; j < 4; ++j) acc[i][j] = 0.f;

    stage_sA(n1in, sA, n, y0, x0, SGm, t);
    __syncthreads();

    {
        const short* __restrict__ Wk = WBe2;
#pragma unroll 1
        for (int ky = 0; ky < 3; ++ky) {
#pragma unroll 1
            for (int kx = 0; kx < 3; ++kx) {
#pragma unroll
                for (int kc = 0; kc < 2; ++kc) {
                    if (kc == 0 || c1 > 32) {
                        bf16x8 af[2], bfr[4];
#pragma unroll
                        for (int nt = 0; nt < 4; ++nt)
                            if (nt * 16 < c2)
                                bfr[nt] = *(const bf16x8*)(Wk + (nt * 16 + lm) * 64 + kc * 32 + q * 8);
#pragma unroll
                        for (int mt = 0; mt < 2; ++mt)
                            af[mt] = *(const bf16x8*)(&sA[saF(w + ky, mt * 16 + lm + kx, kc * 4 + q)]);
#pragma unroll
                        for (int nt = 0; nt < 4; ++nt)
                            if (nt * 16 < c2) {
#pragma unroll
                                for (int mt = 0; mt < 2; ++mt)
                                    acc[mt][nt] = __builtin_amdgcn_mfma_f32_16x16x32_bf16(af[mt], bfr[nt], acc[mt][nt], 0, 0, 0);
                            }
                    }
                }
                Wk += 4096;
            }
        }
    }

    // ---- transposed epilogue: coalesced NCHW stores + skip reads ----
    __syncthreads();                 // sA dead for all waves -> reuse as fp32
    float* __restrict__ sE = (float*)sA;   // [64 rows (w*16+lm)][stride 33]
    const int y = y0 + w;
    const int xs = t & 31, ys = t >> 5;    // 8 x 32 read layout
#pragma unroll
    for (int nt = 0; nt < 4; ++nt) {
#pragma unroll
        for (int mt = 0; mt < 2; ++mt)
#pragma unroll
            for (int r = 0; r < 4; ++r) {
                const int xp = mt * 16 + q * 4 + r;
                const int oc = nt * 16 + lm;
                const float p3v = __bfloat162float(
                    ((const __hip_bfloat16*)p3in)[((n * 64 + y) * 64 + x0 + xp) * 64 + oc]);
                sE[(w * 16 + lm) * 33 + xp] = acc[mt][nt][r] + bias3[oc] + p3v;
            }
        __syncthreads();
#pragma unroll
        for (int k = 0; k < 8; ++k) {
            const int rw = k * 8 + ys;           // 0..63 = (w-local<<4) + oc-local
            const float vv = sE[rw * 33 + xs];
            const int oc = nt * 16 + (rw & 15), yy = y0 + (rw >> 4);
            const int oi = ((n * 64 + oc) * 64 + yy) * 64 + x0 + xs;
            outp[oi] = vv + skip[oi];   // oc>=c2: acc=bias=p3=0 -> skip only
        }
        __syncthreads();               // sE reuse guard for next nt
    }
}

// ---------------------------------------------------------------------------
extern "C" void kernel_launch(void* const* d_in, const int* in_sizes, int n_in,
                              void* d_out, int out_size, void* d_ws, size_t ws_size,
                              hipStream_t stream) {
    (void)in_sizes; (void)n_in; (void)out_size; (void)ws_size;
    const float* x  = (const float*)d_in[0];
    const float* a1 = (const float*)d_in[1];
    const float* a2 = (const float*)d_in[2];
    const float* w3 = (const float*)d_in[3];
    const float* w1 = (const float*)d_in[4];
    const float* bn = (const float*)d_in[5];
    char* ws = (char*)d_ws;

    short* xT = (short*)(ws + OFF_XT);
    short* n1 = (short*)(ws + OFF_N1);
    short* p3 = (short*)(ws + OFF_P3);

    prep_transform_kernel<<<2560, 256, 0, stream>>>(x, w3, w1, bn, a1, a2, ws);
    const dim3 gc(32, 32);   // (y-tile, x-half) pairs, n
    fused_mid_kernel<<<gc, 256, 0, stream>>>(xT, ws, n1, p3);
    final_conv_kernel<<<gc, 256, 0, stream>>>(n1, ws, x, (float*)d_out);
}

// Round 9
// 134.914 us; speedup vs baseline: 1.1131x; 1.1131x over previous
//
#include <hip/hip_runtime.h>
#include <hip/hip_bf16.h>

#define DI __device__ __forceinline__

typedef __attribute__((ext_vector_type(8))) short bf16x8;   // 8 bf16 = 4 VGPRs (MFMA A/B frag)
typedef __attribute__((ext_vector_type(4))) float f32x4;    // MFMA C/D frag

constexpr int HW = 4096, CHW = 262144;
constexpr int SAS = 72;            // sA ic-stride (36 dwords)

// ---- workspace layout (bytes), all 16B aligned ----
constexpr size_t OFF_N1   = 0;                       // bf16 NHWC relu(n1)     16 MB
constexpr size_t OFF_P3   = 16777216;                // bf16 NHWC p3 = conv1_e1(n2)+b4
constexpr size_t OFF_WB3  = 33554432;                // bf16 [3][9][64oc][64ic]  (frag order)
constexpr size_t OFF_WB1  = OFF_WB3 + 221184;        // bf16 [2][64oc][64ic]
constexpr size_t OFF_BIAS = OFF_WB1 + 16384;         // f32 [5][64]
constexpr size_t OFF_CC   = OFF_BIAS + 1280;         // int[2]

DI int argmax8(const float* __restrict__ a) {
    int best = 0; float bv = a[0];
#pragma unroll
    for (int i = 1; i < 8; ++i) { float v = a[i]; if (v > bv) { bv = v; best = i; } }
    return best;
}

DI short f2bf(float v) {   // fp32 -> bf16 bits (RNE)
    __hip_bfloat16 h = __float2bfloat16(v);
    return __builtin_bit_cast(short, h);
}

// ---------------------------------------------------------------------------
// prep: c1,c2; weights -> bf16 [edge][kpos][oc][ic] frag order, BN scale +
// channel masks folded; per-edge bias (out-masked). Tiny kernel (~3 us).
// ---------------------------------------------------------------------------
__global__ __launch_bounds__(256) void prep_kernel(
    const float* __restrict__ w3, const float* __restrict__ w1,
    const float* __restrict__ bn, const float* __restrict__ a1,
    const float* __restrict__ a2, char* __restrict__ ws) {
    short* __restrict__ wb3  = (short*)(ws + OFF_WB3);
    short* __restrict__ wb1  = (short*)(ws + OFF_WB1);
    float* __restrict__ bias = (float*)(ws + OFF_BIAS);
    int*   __restrict__ cc   = (int*)(ws + OFF_CC);
    const int c1 = 8 * (argmax8(a1) + 1);
    const int c2 = 8 * (argmax8(a2) + 1);

    const int idx = blockIdx.x * 256 + threadIdx.x;
    if (idx < 110592) {                       // wb3 flat = ((e*9+kp)*64+oc)*64+ic
        const int e = idx / 36864, rem = idx % 36864;
        const int kp = rem >> 12, oc = (rem >> 6) & 63, ic = rem & 63;
        const int bnrow = (e == 0) ? 0 : (e == 1) ? 1 : 3;
        const float g = bn[(bnrow * 4 + 0) * 64 + oc];
        const float v = bn[(bnrow * 4 + 3) * 64 + oc];
        const float s = g * rsqrtf(v + 1e-5f);
        const float wv = w3[((e * 64 + oc) * 64 + ic) * 9 + kp];
        wb3[idx] = (oc < c2 && ic < c1) ? f2bf(wv * s) : (short)0;
    } else if (idx < 118784) {                // wb1 flat = (e*64+oc)*64+ic
        const int j = idx - 110592;
        const int e = j >> 12, oc = (j >> 6) & 63, ic = j & 63;
        const int bnrow = (e == 0) ? 2 : 4;
        const float g = bn[(bnrow * 4 + 0) * 64 + oc];
        const float v = bn[(bnrow * 4 + 3) * 64 + oc];
        const float s = g * rsqrtf(v + 1e-5f);
        wb1[j] = (oc < c2 && ic < c1) ? f2bf(w1[(e * 64 + oc) * 64 + ic] * s) : (short)0;
    } else if (idx < 119104) {                // bias
        const int j = idx - 118784;
        const int e = j >> 6, oc = j & 63;
        const float g = bn[(e * 4 + 0) * 64 + oc];
        const float b = bn[(e * 4 + 1) * 64 + oc];
        const float m = bn[(e * 4 + 2) * 64 + oc];
        const float v = bn[(e * 4 + 3) * 64 + oc];
        bias[j] = (oc < c2) ? (b - m * g * rsqrtf(v + 1e-5f)) : 0.f;
    } else if (idx == 119104) {
        cc[0] = c1; cc[1] = c2;
    }
}

// ---------------------------------------------------------------------------
// stage sA (6 rows x 66 cols x live ic) DIRECTLY from fp32 NCHW x with fused
// relu + bf16 convert + transpose. Per (row, icg) unit: 8 coalesced 256 B row
// loads (one per ic of the group) packed to bf16x8, one ds_write_b128.
// x-halo columns (px=-1,64) are always OOB at full-width tiles -> pre-zeroed.
// ---------------------------------------------------------------------------
DI void stage_sA_from_x(const float* __restrict__ x, short* __restrict__ sA,
                        int n, int y0, int SGm, int t) {
    const int w = t >> 6, l = t & 63;
    if (t < 96) {   // zero halo cols c=0 and c=65: (r<6, chp<2, sg<8)
        const int r = t >> 4, chp = (t >> 3) & 1, sg = t & 7;
        *(bf16x8*)(&sA[(r * 66 + chp * 65) * SAS + sg * 8]) = (bf16x8)0;
    }
#pragma unroll 1
    for (int u = w; u < 48; u += 4) {          // (row r = u>>3, ic-group icg = u&7)
        const int r = u >> 3, icg = u & 7;
        if (icg < SGm) {                        // wave-uniform ic cull
            const int gy = y0 + r - 1;
            const float* __restrict__ src = x + (((size_t)n * 64 + icg * 8) * 64 + gy) * 64 + l;
            bf16x8 pk = (bf16x8)0;
            if ((unsigned)gy < 64u) {           // wave-uniform y-halo check
#pragma unroll
                for (int j = 0; j < 8; ++j)
                    pk[j] = f2bf(fmaxf(src[j * HW], 0.f));
            }
            *(bf16x8*)(&sA[(r * 66 + l + 1) * SAS + icg * 8]) = pk;
        }
    }
}

// stage sA from a bf16 NHWC tensor (K2: n1 with halo)
DI void stage_sA(const short* __restrict__ src, short* __restrict__ sA,
                 int n, int y0, int SGm, int t) {
    for (int idx = t; idx < 6 * 66 * 8; idx += 256) {
        const int r = idx / 528, rem = idx - r * 528, c = rem >> 3, sg = rem & 7;
        if (sg < SGm) {
            const int gy = y0 + r - 1, gx = c - 1;
            bf16x8 v = 0;
            if ((unsigned)gy < 64u && (unsigned)gx < 64u)
                v = *(const bf16x8*)(src + ((n * 64 + gy) * 64 + gx) * 64 + sg * 8);
            *(bf16x8*)(&sA[(r * 66 + c) * SAS + sg * 8]) = v;
        }
    }
}

// coalesced store of one 64-px row (sA cols 1..64, all 64 ch) to NHWC global.
DI void store_row_from_sA(const short* __restrict__ sA, int row,
                          short* __restrict__ dst, int l) {
#pragma unroll
    for (int i = 0; i < 8; ++i) {
        const int c = i * 8 + (l >> 3), sg = l & 7;
        *(bf16x8*)(dst + c * 64 + sg * 8) =
            *(const bf16x8*)(&sA[(row * 66 + c + 1) * SAS + sg * 8]);
    }
}

// ---------------------------------------------------------------------------
// K1: fused mid, staging straight from x (K0 deleted). Dual conv3 (e0->acc1,
// e1->acc2) off one sA staging; per-wave chain: n1 -> own sA row -> coalesced
// global store -> conv1_e0 into acc2 (=n2) -> conv1_e1 -> p3 -> store.
// All register-array indices compile-time (R2 spill lesson); channel culls
// are wave-uniform guards.
// ---------------------------------------------------------------------------
__global__ __launch_bounds__(256, 2) void fused_mid_kernel(
    const float* __restrict__ x, const char* __restrict__ ws,
    short* __restrict__ n1out, short* __restrict__ p3out) {
    __shared__ __align__(16) short sA[6 * 66 * SAS];   // 55.7 KB
    const int t = threadIdx.x, w = t >> 6, l = t & 63, lm = l & 15, q = l >> 4;
    const int y0 = blockIdx.x * 4, n = blockIdx.y;
    const int* cc = (const int*)(ws + OFF_CC);
    const int c1 = __builtin_amdgcn_readfirstlane(cc[0]);
    const int c2 = __builtin_amdgcn_readfirstlane(cc[1]);
    const int SGm = (c1 > 32) ? 8 : 4;
    const float* __restrict__ bias = (const float*)(ws + OFF_BIAS);
    const short* __restrict__ WBe0 = (const short*)(ws + OFF_WB3);
    const short* __restrict__ WBe1 = WBe0 + 36864;
    const short* __restrict__ W1e0 = (const short*)(ws + OFF_WB1);
    const short* __restrict__ W1e1 = W1e0 + 4096;

    f32x4 acc1[4][4], acc2[4][4];
#pragma unroll
    for (int i = 0; i < 4; ++i)
#pragma unroll
        for (int j = 0; j < 4; ++j) { acc1[i][j] = 0.f; acc2[i][j] = 0.f; }

    stage_sA_from_x(x, sA, n, y0, SGm, t);
    __syncthreads();

    // ---- dual conv3 K-loop (barrier-free, sA read-only) ----
    {
        const short* __restrict__ W0 = WBe0;
        const short* __restrict__ W1 = WBe1;
#pragma unroll 1
        for (int ky = 0; ky < 3; ++ky) {
#pragma unroll 1
            for (int kx = 0; kx < 3; ++kx) {
#pragma unroll
                for (int kc = 0; kc < 2; ++kc) {
                    if (kc == 0 || c1 > 32) {
                        bf16x8 af[4], b0[4], b1[4];
#pragma unroll
                        for (int nt = 0; nt < 4; ++nt)
                            if (nt * 16 < c2) {
                                b0[nt] = *(const bf16x8*)(W0 + (nt * 16 + lm) * 64 + kc * 32 + q * 8);
                                b1[nt] = *(const bf16x8*)(W1 + (nt * 16 + lm) * 64 + kc * 32 + q * 8);
                            }
#pragma unroll
                        for (int mt = 0; mt < 4; ++mt)
                            af[mt] = *(const bf16x8*)(&sA[((w + ky) * 66 + (mt * 16 + lm + kx)) * SAS + kc * 32 + q * 8]);
#pragma unroll
                        for (int nt = 0; nt < 4; ++nt)
                            if (nt * 16 < c2) {
#pragma unroll
                                for (int mt = 0; mt < 4; ++mt) {
                                    acc1[mt][nt] = __builtin_amdgcn_mfma_f32_16x16x32_bf16(af[mt], b0[nt], acc1[mt][nt], 0, 0, 0);
                                    acc2[mt][nt] = __builtin_amdgcn_mfma_f32_16x16x32_bf16(af[mt], b1[nt], acc2[mt][nt], 0, 0, 0);
                                }
                            }
                    }
                }
                W0 += 4096; W1 += 4096;
            }
        }
    }

    __syncthreads();   // all waves done reading stage-1 sA; rows become wave-private

    const int y = y0 + w;
    short* __restrict__ n1row = n1out + (size_t)((n * 64 + y) * 64) * 64;
    short* __restrict__ p3row = p3out + (size_t)((n * 64 + y) * 64) * 64;

    // epi1: n1 = relu(acc1 + b0) -> own sA row (cols 1..64, all 64 oc)
#pragma unroll
    for (int nt = 0; nt < 4; ++nt) {
        const int oc = nt * 16 + lm;
        const float bv = bias[oc];
#pragma unroll
        for (int mt = 0; mt < 4; ++mt)
#pragma unroll
            for (int r = 0; r < 4; ++r) {
                const int xp = mt * 16 + q * 4 + r;
                sA[((w + 1) * 66 + xp + 1) * SAS + oc] = f2bf(fmaxf(acc1[mt][nt][r] + bv, 0.f));
            }
    }
    store_row_from_sA(sA, w + 1, n1row, l);

    // conv1_e0(n1) += acc2 (own row)
#pragma unroll
    for (int kc = 0; kc < 2; ++kc) {
        if (kc == 0 || c1 > 32) {
            bf16x8 af[4], bfr[4];
#pragma unroll
            for (int mt = 0; mt < 4; ++mt)
                af[mt] = *(const bf16x8*)(&sA[((w + 1) * 66 + (mt * 16 + lm + 1)) * SAS + kc * 32 + q * 8]);
#pragma unroll
            for (int nt = 0; nt < 4; ++nt)
                if (nt * 16 < c2)
                    bfr[nt] = *(const bf16x8*)(W1e0 + (nt * 16 + lm) * 64 + kc * 32 + q * 8);
#pragma unroll
            for (int nt = 0; nt < 4; ++nt)
                if (nt * 16 < c2) {
#pragma unroll
                    for (int mt = 0; mt < 4; ++mt)
                        acc2[mt][nt] = __builtin_amdgcn_mfma_f32_16x16x32_bf16(af[mt], bfr[nt], acc2[mt][nt], 0, 0, 0);
                }
        }
    }

    // epi2: n2 = relu(acc2 + b1 + b2) -> own sA row
#pragma unroll
    for (int nt = 0; nt < 4; ++nt) {
        const int oc = nt * 16 + lm;
        const float bv = bias[64 + oc] + bias[128 + oc];
#pragma unroll
        for (int mt = 0; mt < 4; ++mt)
#pragma unroll
            for (int r = 0; r < 4; ++r) {
                const int xp = mt * 16 + q * 4 + r;
                sA[((w + 1) * 66 + xp + 1) * SAS + oc] = f2bf(fmaxf(acc2[mt][nt][r] + bv, 0.f));
            }
    }

    // conv1_e1(n2) -> acc3 (reuses acc1's registers)
    {
        f32x4 acc3[4][4];
#pragma unroll
        for (int i = 0; i < 4; ++i)
#pragma unroll
            for (int j = 0; j < 4; ++j) acc3[i][j] = 0.f;
#pragma unroll
        for (int kc = 0; kc < 2; ++kc) {
            if (kc == 0 || c1 > 32) {
                bf16x8 af[4], bfr[4];
#pragma unroll
                for (int mt = 0; mt < 4; ++mt)
                    af[mt] = *(const bf16x8*)(&sA[((w + 1) * 66 + (mt * 16 + lm + 1)) * SAS + kc * 32 + q * 8]);
#pragma unroll
                for (int nt = 0; nt < 4; ++nt)
                    if (nt * 16 < c2)
                        bfr[nt] = *(const bf16x8*)(W1e1 + (nt * 16 + lm) * 64 + kc * 32 + q * 8);
#pragma unroll
                for (int nt = 0; nt < 4; ++nt)
                    if (nt * 16 < c2) {
#pragma unroll
                        for (int mt = 0; mt < 4; ++mt)
                            acc3[mt][nt] = __builtin_amdgcn_mfma_f32_16x16x32_bf16(af[mt], bfr[nt], acc3[mt][nt], 0, 0, 0);
                    }
            }
        }
#pragma unroll
        for (int nt = 0; nt < 4; ++nt) {
            const int oc = nt * 16 + lm;
            const float bv = bias[256 + oc];
#pragma unroll
            for (int mt = 0; mt < 4; ++mt)
#pragma unroll
                for (int r = 0; r < 4; ++r) {
                    const int xp = mt * 16 + q * 4 + r;
                    sA[((w + 1) * 66 + xp + 1) * SAS + oc] = f2bf(acc3[mt][nt][r] + bv);
                }
        }
        store_row_from_sA(sA, w + 1, p3row, l);
    }
}

// ---------------------------------------------------------------------------
// K2: d_out = x + conv3_e2(n1) + p3, LDS-transposed coalesced epilogue.
// ---------------------------------------------------------------------------
__global__ __launch_bounds__(256, 2) void final_conv_kernel(
    const short* __restrict__ n1in, const char* __restrict__ ws,
    const float* __restrict__ skip, float* __restrict__ outp) {
    __shared__ __align__(16) short sA[6 * 66 * SAS];
    const int t = threadIdx.x, w = t >> 6, l = t & 63, lm = l & 15, q = l >> 4;
    const int y0 = blockIdx.x * 4, n = blockIdx.y;
    const int* cc = (const int*)(ws + OFF_CC);
    const int c1 = __builtin_amdgcn_readfirstlane(cc[0]);
    const int c2 = __builtin_amdgcn_readfirstlane(cc[1]);
    const int SGm = (c1 > 32) ? 8 : 4;
    const float* __restrict__ bias3 = (const float*)(ws + OFF_BIAS) + 192;
    const short* __restrict__ WBe2 = (const short*)(ws + OFF_WB3) + 2 * 36864;
    const short* __restrict__ p3in = (const short*)(ws + OFF_P3);

    f32x4 acc[4][4];
#pragma unroll
    for (int i = 0; i < 4; ++i)
#pragma unroll
        for (int j = 0; j < 4; ++j) acc[i][j] = 0.f;

    stage_sA(n1in, sA, n, y0, SGm, t);
    __syncthreads();

    {
        const short* __restrict__ Wk = WBe2;
#pragma unroll 1
        for (int ky = 0; ky < 3; ++ky) {
#pragma unroll 1
            for (int kx = 0; kx < 3; ++kx) {
#pragma unroll
                for (int kc = 0; kc < 2; ++kc) {
                    if (kc == 0 || c1 > 32) {
                        bf16x8 af[4], bfr[4];
#pragma unroll
                        for (int nt = 0; nt < 4; ++nt)
                            if (nt * 16 < c2)
                                bfr[nt] = *(const bf16x8*)(Wk + (nt * 16 + lm) * 64 + kc * 32 + q * 8);
#pragma unroll
                        for (int mt = 0; mt < 4; ++mt)
                            af[mt] = *(const bf16x8*)(&sA[((w + ky) * 66 + (mt * 16 + lm + kx)) * SAS + kc * 32 + q * 8]);
#pragma unroll
                        for (int nt = 0; nt < 4; ++nt)
                            if (nt * 16 < c2) {
#pragma unroll
                                for (int mt = 0; mt < 4; ++mt)
                                    acc[mt][nt] = __builtin_amdgcn_mfma_f32_16x16x32_bf16(af[mt], bfr[nt], acc[mt][nt], 0, 0, 0);
                            }
                    }
                }
                Wk += 4096;
            }
        }
    }

    // ---- transposed epilogue: coalesced NCHW stores + skip reads ----
    __syncthreads();                 // sA dead for all waves -> reuse as fp32
    float* __restrict__ sE = (float*)sA;   // [64 rows (w*16+lm)][stride 67]
    const int y = y0 + w;
    const int xs = t & 63, ys = t >> 6;
#pragma unroll
    for (int nt = 0; nt < 4; ++nt) {
#pragma unroll
        for (int mt = 0; mt < 4; ++mt)
#pragma unroll
            for (int r = 0; r < 4; ++r) {
                const int xp = mt * 16 + q * 4 + r;
                const int oc = nt * 16 + lm;
                const float p3v = __bfloat162float(
                    ((const __hip_bfloat16*)p3in)[((n * 64 + y) * 64 + xp) * 64 + oc]);
                sE[(w * 16 + lm) * 67 + xp] = acc[mt][nt][r] + bias3[oc] + p3v;
            }
        __syncthreads();
#pragma unroll
        for (int ocl = 0; ocl < 16; ++ocl) {
            const float vv = sE[(ys * 16 + ocl) * 67 + xs];
            const int oi = ((n * 64 + nt * 16 + ocl) * 64 + (y0 + ys)) * 64 + xs;
            outp[oi] = vv + skip[oi];   // oc>=c2: acc=bias=p3=0 -> skip only
        }
        __syncthreads();               // sE reuse guard for next nt
    }
}

// ---------------------------------------------------------------------------
extern "C" void kernel_launch(void* const* d_in, const int* in_sizes, int n_in,
                              void* d_out, int out_size, void* d_ws, size_t ws_size,
                              hipStream_t stream) {
    (void)in_sizes; (void)n_in; (void)out_size; (void)ws_size;
    const float* x  = (const float*)d_in[0];
    const float* a1 = (const float*)d_in[1];
    const float* a2 = (const float*)d_in[2];
    const float* w3 = (const float*)d_in[3];
    const float* w1 = (const float*)d_in[4];
    const float* bn = (const float*)d_in[5];
    char* ws = (char*)d_ws;

    short* n1 = (short*)(ws + OFF_N1);
    short* p3 = (short*)(ws + OFF_P3);

    prep_kernel<<<466, 256, 0, stream>>>(w3, w1, bn, a1, a2, ws);
    const dim3 gc(16, 32);   // y-tiles, n
    fused_mid_kernel<<<gc, 256, 0, stream>>>(x, ws, n1, p3);
    final_conv_kernel<<<gc, 256, 0, stream>>>(n1, ws, x, (float*)d_out);
}